// Round 10
// baseline (200.809 us; speedup 1.0000x reference)
//
#include <hip/hip_runtime.h>

// ---------------------------------------------------------------------------
// GCN 2-layer forward, round 22.
// Round-21 post-mortem: NEUTRAL 200.2 (vs 198.0 r17). Launch gaps were not
// the slack. Structural audit: agg pair ~80us; hbuf 12.8MB random-gathered
// by all 8 XCDs -> ~102MB L2-miss traffic per agg is IRREDUCIBLE (measured
// FETCH 90-97MB: at the bound). Rate only ~2.2TB/s with VALUBusy 12% ->
// latency-bound, not BW-bound. Only 2 H-rows in flight per 8-lane group.
// Round-22 delta (ONE mechanism): 4-edge software pipeline in k_agg.
//   * k_bfill: cnt padded to x4 (pads = sentinel row N, dinv[N]=0 -> exact
//     zero contribution; per-accumulator FP order unchanged -> absmax
//     bit-identical).
//   * k_agg: process 4 edges/iter; next iter's int4 csrc + 4 dinv + 4 H
//     rows issued before consuming current 4 -> 4-8 rows in flight/group.
//     Named scalars only (no runtime-indexed reg arrays). VGPR ~60: no
//     occupancy impact.
// Rest byte-identical to r21. Pipeline: [count||gemm1], scan, scatter,
// bfill, agg1, gemm2, agg2.
// ---------------------------------------------------------------------------

#define NPB 32       // nodes per block (agg): 256 thr / 8-lane groups
#define BSH 8        // bucket shift: 256 nodes per bucket
#define BSZ 256
#define PTILE 4096   // messages per partition tile
#define CAP 6144     // fixed bucket capacity (slots)
#define PADALLOW 3856
#define CROW (CAP + PADALLOW)  // per-bucket csrc region
#define GEMMB 1024   // gemm1 blocks inside k_cntgm

typedef __attribute__((ext_vector_type(8))) short bf16x8;
typedef __attribute__((ext_vector_type(4))) float f32x4;

__device__ __forceinline__ unsigned bf16_rne(float f) {
    unsigned b = __float_as_uint(f);
    return (b + 0x7fffu + ((b >> 16) & 1u)) >> 16;
}
__device__ __forceinline__ float bf16_lo(unsigned u) { return __uint_as_float(u << 16); }
__device__ __forceinline__ float bf16_hi(unsigned u) { return __uint_as_float(u & 0xffff0000u); }

// H[row] = (X[row] @ W) UNSCALED, bf16 out; zero sentinel row at N.
template <bool BF16IN, int NT>
__device__ __forceinline__ void gemm_body(const void* __restrict__ Xv,
                                          const float* __restrict__ W,
                                          unsigned* __restrict__ Hout,
                                          int N, int nSlabs, int blkLocal,
                                          int nBlkLocal, float* SMEM) {
    int t = threadIdx.x;
    int lane = t & 63, w = t >> 6;
    int nn = lane & 15, kq = lane >> 4;
    constexpr int NW = NT / 64;

    for (int i = t; i < 1024; i += NT) ((float4*)SMEM)[i] = ((const float4*)W)[i];
    __syncthreads();
    bf16x8 Bf[2][4];
    #pragma unroll
    for (int kt = 0; kt < 2; kt++) {
        #pragma unroll
        for (int ct = 0; ct < 4; ct++) {
            union { bf16x8 v; unsigned short s[8]; } u;
            #pragma unroll
            for (int j = 0; j < 8; j++) {
                int k = kt * 32 + kq * 8 + j;
                u.s[j] = (unsigned short)bf16_rne(SMEM[k * 64 + ct * 16 + nn]);
            }
            Bf[kt][ct] = u.v;
        }
    }
    __syncthreads();  // W region dead; SMEM becomes per-wave transpose scratch

    float* outT = SMEM + w * 1056;  // 16 rows x 66 floats

    for (int slab = blkLocal * NW + w; slab < nSlabs; slab += nBlkLocal * NW) {
        int row0 = slab * 16;
        int rowA = min(row0 + nn, N - 1);
        bf16x8 A0, A1;
        if (BF16IN) {
            const uint4* X = (const uint4*)Xv;  // row = 8 uint4
            union { uint4 u; bf16x8 v; } a0, a1;
            a0.u = X[(size_t)rowA * 8 + kq];
            a1.u = X[(size_t)rowA * 8 + 4 + kq];
            A0 = a0.v; A1 = a1.v;
        } else {
            const float4* X = (const float4*)Xv;  // row = 16 float4
            float4 f0 = X[(size_t)rowA * 16 + kq * 2];
            float4 f1 = X[(size_t)rowA * 16 + kq * 2 + 1];
            float4 f2 = X[(size_t)rowA * 16 + 8 + kq * 2];
            float4 f3 = X[(size_t)rowA * 16 + 8 + kq * 2 + 1];
            union { bf16x8 v; unsigned short s[8]; } a0, a1;
            a0.s[0] = (unsigned short)bf16_rne(f0.x); a0.s[1] = (unsigned short)bf16_rne(f0.y);
            a0.s[2] = (unsigned short)bf16_rne(f0.z); a0.s[3] = (unsigned short)bf16_rne(f0.w);
            a0.s[4] = (unsigned short)bf16_rne(f1.x); a0.s[5] = (unsigned short)bf16_rne(f1.y);
            a0.s[6] = (unsigned short)bf16_rne(f1.z); a0.s[7] = (unsigned short)bf16_rne(f1.w);
            a1.s[0] = (unsigned short)bf16_rne(f2.x); a1.s[1] = (unsigned short)bf16_rne(f2.y);
            a1.s[2] = (unsigned short)bf16_rne(f2.z); a1.s[3] = (unsigned short)bf16_rne(f2.w);
            a1.s[4] = (unsigned short)bf16_rne(f3.x); a1.s[5] = (unsigned short)bf16_rne(f3.y);
            a1.s[6] = (unsigned short)bf16_rne(f3.z); a1.s[7] = (unsigned short)bf16_rne(f3.w);
            A0 = a0.v; A1 = a1.v;
        }

        f32x4 acc[4];
        #pragma unroll
        for (int ct = 0; ct < 4; ct++) acc[ct] = (f32x4){0.f, 0.f, 0.f, 0.f};
        #pragma unroll
        for (int ct = 0; ct < 4; ct++) {
            acc[ct] = __builtin_amdgcn_mfma_f32_16x16x32_bf16(A0, Bf[0][ct], acc[ct], 0, 0, 0);
            acc[ct] = __builtin_amdgcn_mfma_f32_16x16x32_bf16(A1, Bf[1][ct], acc[ct], 0, 0, 0);
        }

        #pragma unroll
        for (int reg = 0; reg < 4; reg++) {
            int r = kq * 4 + reg;
            #pragma unroll
            for (int ct = 0; ct < 4; ct++) {
                outT[r * 66 + ct * 16 + nn] = acc[ct][reg];
            }
        }
        int rr = lane >> 2;
        int c0 = (lane & 3) * 16;
        int orow = row0 + rr;
        if (orow < N) {
            unsigned pk[8];
            #pragma unroll
            for (int i = 0; i < 8; i++) {
                float lo = outT[rr * 66 + c0 + 2 * i];
                float hi = outT[rr * 66 + c0 + 2 * i + 1];
                pk[i] = bf16_rne(lo) | (bf16_rne(hi) << 16);
            }
            uint4* dst = (uint4*)Hout + (size_t)orow * 8 + (lane & 3) * 2;
            dst[0] = make_uint4(pk[0], pk[1], pk[2], pk[3]);
            dst[1] = make_uint4(pk[4], pk[5], pk[6], pk[7]);
        } else if (orow == N) {  // zero sentinel row
            uint4* dst = (uint4*)Hout + (size_t)N * 8 + (lane & 3) * 2;
            dst[0] = make_uint4(0, 0, 0, 0);
            dst[1] = make_uint4(0, 0, 0, 0);
        }
    }
}

// Fused: per-tile bucket histogram (blocks < numTiles) || gemm1 (next GEMMB).
__global__ __launch_bounds__(512) void k_cntgm(const int* __restrict__ coli,
                                               int E, int N, int NB, int numTiles,
                                               int* __restrict__ tcnt,
                                               const float* __restrict__ x,
                                               const float* __restrict__ W1,
                                               unsigned* __restrict__ hbuf,
                                               int nSlabs) {
    __shared__ float SMEM[8448];  // gemm: W + 8-wave scratch; count: hist
    int bid = blockIdx.x;
    if (bid >= numTiles) {
        gemm_body<false, 512>(x, W1, hbuf, N, nSlabs, bid - numTiles, GEMMB, SMEM);
        return;
    }
    int* hist = (int*)SMEM;
    int t = threadIdx.x;
    int T = E + N;
    int tstart = bid * PTILE;
    int m = min(PTILE, T - tstart);
    for (int b = t; b < NB; b += 512) hist[b] = 0;
    __syncthreads();
    for (int i = t; i < m; i += 512) {
        int g = tstart + i;
        int c = (g < E) ? coli[g] : (g - E);
        atomicAdd(&hist[c >> BSH], 1);
    }
    __syncthreads();
    for (int b = t; b < NB; b += 512) tcnt[(size_t)bid * NB + b] = hist[b];
}

// Block-per-bucket exclusive scan over tiles (chunked, wave-shuffle).
__global__ __launch_bounds__(512) void k_scan(int* __restrict__ tcnt,
                                              int* __restrict__ btot,
                                              int NB, int numTiles) {
    __shared__ int wsum[8];
    int b = blockIdx.x;
    int t = threadIdx.x;
    int lane = t & 63, wid = t >> 6;
    int base = 0;
    for (int c0 = 0; c0 < numTiles; c0 += 512) {
        int tt = c0 + t;
        int v = (tt < numTiles) ? tcnt[(size_t)tt * NB + b] : 0;
        int inc = v;
        #pragma unroll
        for (int d = 1; d < 64; d <<= 1) {
            int o = __shfl_up(inc, d);
            if (lane >= d) inc += o;
        }
        if (lane == 63) wsum[wid] = inc;
        __syncthreads();
        int woff = 0, ctot = 0;
        #pragma unroll
        for (int i = 0; i < 8; i++) {
            int s = wsum[i];
            if (i < wid) woff += s;
            ctot += s;
        }
        if (tt < numTiles) tcnt[(size_t)tt * NB + b] = b * CAP + base + woff + inc - v;
        base += ctot;
        __syncthreads();
    }
    if (t == 0) btot[b] = base;
}

// Scatter: LDS counting sort per tile, coalesced pairs writes.
__global__ __launch_bounds__(512) void k_scatter(const int* __restrict__ rowi,
                                                 const int* __restrict__ coli,
                                                 int E, int N, int NB, int numTiles,
                                                 const int* __restrict__ tcnt,
                                                 unsigned* __restrict__ pairs) {
    __shared__ int hist[512];
    __shared__ int lbase[512];
    __shared__ int gbase[512];
    __shared__ unsigned sorted[PTILE];
    __shared__ unsigned short sbkt[PTILE];
    __shared__ int wsum[8];
    int t = threadIdx.x;
    int T = E + N;
    int tile = blockIdx.x;
    int tstart = tile * PTILE;
    int m = min(PTILE, T - tstart);
    int lane = t & 63, wid = t >> 6;
    for (int b = t; b < NB; b += 512) {
        hist[b] = 0;
        gbase[b] = tcnt[(size_t)tile * NB + b];
    }
    __syncthreads();
    int c_reg[8];
    #pragma unroll
    for (int k = 0; k < 8; k++) {
        int i = t + k * 512;
        int c = 0;
        if (i < m) {
            int g = tstart + i;
            c = (g < E) ? coli[g] : (g - E);
            atomicAdd(&hist[c >> BSH], 1);
        }
        c_reg[k] = c;
    }
    __syncthreads();
    {   // block exclusive scan of hist -> lbase
        int v = (t < NB) ? hist[t] : 0;
        int inc = v;
        #pragma unroll
        for (int d = 1; d < 64; d <<= 1) {
            int o = __shfl_up(inc, d);
            if (lane >= d) inc += o;
        }
        if (lane == 63) wsum[wid] = inc;
        __syncthreads();
        int woff = 0;
        for (int i = 0; i < wid; i++) woff += wsum[i];
        if (t < NB) lbase[t] = woff + inc - v;
        __syncthreads();
    }
    for (int b = t; b < NB; b += 512) hist[b] = 0;  // reuse as cursors
    __syncthreads();
    #pragma unroll
    for (int k = 0; k < 8; k++) {
        int i = t + k * 512;
        if (i < m) {
            int g = tstart + i;
            int c = c_reg[k];
            int r = (g < E) ? rowi[g] : c;  // self-loop tail has r == c
            int b = c >> BSH;
            int lr = atomicAdd(&hist[b], 1);
            int pos = lbase[b] + lr;
            sorted[pos] = (unsigned)r | ((unsigned)(c & (BSZ - 1)) << 24);
            sbkt[pos] = (unsigned short)b;
        }
    }
    __syncthreads();
    for (int j = t; j < m; j += 512) {
        int b = sbkt[j];
        pairs[gbase[b] + (j - lbase[b])] = sorted[j];
    }
}

// One block per bucket: per-node histogram, padded scan, build csrc in LDS,
// coalesced copy out. cnt padded to x4 for the agg 4-edge pipeline.
__global__ __launch_bounds__(1024) void k_bfill(const unsigned* __restrict__ pairs,
                                                const int* __restrict__ btot,
                                                int N,
                                                int* __restrict__ offsets,
                                                int* __restrict__ cnt,
                                                float* __restrict__ dinv,
                                                int* __restrict__ csrc) {
    __shared__ int scnt[BSZ];
    __shared__ int scur[BSZ];
    __shared__ int wsum[4];
    __shared__ int scsrc[CROW];
    int b = blockIdx.x;
    int t = threadIdx.x;
    int ebeg = b * CAP;
    int m = btot[b];
    int pbase = b * CROW;
    int lane = t & 63, wid = t >> 6;
    if (b == 0 && t == 0) dinv[N] = 0.0f;  // sentinel row scale
    if (t < BSZ) scnt[t] = 0;
    __syncthreads();
    for (int i = t; i < m; i += 1024) atomicAdd(&scnt[pairs[ebeg + i] >> 24], 1);
    __syncthreads();
    int cval = 0, pc = 0, inc = 0;
    if (t < BSZ) {
        cval = scnt[t];
        pc = (cval + 15) & ~15;
        inc = pc;
        #pragma unroll
        for (int d = 1; d < 64; d <<= 1) {
            int o = __shfl_up(inc, d);
            if (lane >= d) inc += o;
        }
        if (lane == 63) wsum[wid] = inc;
    }
    __syncthreads();
    if (t < BSZ) {
        int woff = 0;
        for (int i = 0; i < wid; i++) woff += wsum[i];
        int offl = woff + inc - pc;
        int v = (b << BSH) + t;
        if (v < N) {
            offsets[v] = pbase + offl;
            cnt[v] = (cval + 3) & ~3;       // round to x4 for agg pipeline
            dinv[v] = rsqrtf((float)cval);
        }
        scur[t] = offl;
        for (int i = offl + cval; i < offl + pc; i++) scsrc[i] = N;  // sentinels
    }
    __syncthreads();
    for (int i = t; i < m; i += 1024) {
        unsigned pk = pairs[ebeg + i];
        int slot = atomicAdd(&scur[pk >> 24], 1);
        scsrc[slot] = (int)(pk & 0xFFFFFFu);
    }
    __syncthreads();
    int tot = wsum[0] + wsum[1] + wsum[2] + wsum[3];
    for (int j = t; j < tot; j += 1024) csrc[pbase + j] = scsrc[j];
}

// Solo gemm kernel (layer 2): H = (abuf @ W2) unscaled.
template <bool BF16IN>
__global__ __launch_bounds__(256) void k_gemm(const void* __restrict__ Xv,
                                              const float* __restrict__ W,
                                              unsigned* __restrict__ Hout,
                                              int N, int nSlabs, int nBlk) {
    __shared__ float SMEM[4224];
    gemm_body<BF16IN, 256>(Xv, W, Hout, N, nSlabs, blockIdx.x, nBlk, SMEM);
}

// out[v] = epi( dinv[v] * sum_j dinv[src_j]*H[src_j] + bias )
// 4-edge software pipeline: next iter's int4 csrc + 4 dinv + 4 H rows are
// issued before the current 4 rows are consumed -> 4-8 rows in flight per
// 8-lane group. deg is a multiple of 4 (sentinel-padded; dinv[N]=0).
template <bool RELU_BF16OUT>
__global__ __launch_bounds__(256) void k_agg(const uint4* __restrict__ H,
                                             const int* __restrict__ offsets,
                                             const int* __restrict__ cnt,
                                             const int* __restrict__ csrc,
                                             const float* __restrict__ dinv,
                                             const float* __restrict__ bias,
                                             void* __restrict__ outv, int N) {
    int t = threadIdx.x;
    int fl = t & 7;
    int v = blockIdx.x * NPB + (t >> 3);
    if (v >= N) return;
    int beg = offsets[v];                  // 16-aligned
    int deg = cnt[v];                      // multiple of 4, >= 4
    const int4* cs4 = (const int4*)(csrc + beg);
    const char* hb = (const char*)H + ((unsigned)fl << 4);

    float a0 = 0.f, a1 = 0.f, a2 = 0.f, a3 = 0.f;
    float a4 = 0.f, a5 = 0.f, a6 = 0.f, a7 = 0.f;

#define ROW(R) (*(const uint4*)(hb + ((unsigned)(R) << 7)))
#define ACC8(DD, D) do {                                                    \
        uint4 dd = (DD);                                                    \
        a0 = fmaf(D, bf16_lo(dd.x), a0); a1 = fmaf(D, bf16_hi(dd.x), a1);   \
        a2 = fmaf(D, bf16_lo(dd.y), a2); a3 = fmaf(D, bf16_hi(dd.y), a3);   \
        a4 = fmaf(D, bf16_lo(dd.z), a4); a5 = fmaf(D, bf16_hi(dd.z), a5);   \
        a6 = fmaf(D, bf16_lo(dd.w), a6); a7 = fmaf(D, bf16_hi(dd.w), a7);   \
    } while (0)

    int nIt = deg >> 2;
    int4 s = cs4[0];
    float e0 = dinv[s.x], e1 = dinv[s.y], e2 = dinv[s.z], e3 = dinv[s.w];
    uint4 h0 = ROW(s.x), h1 = ROW(s.y), h2 = ROW(s.z), h3 = ROW(s.w);
    for (int it = 1; it < nIt; ++it) {
        int4 ns = cs4[it];                 // csrc 1 iter ahead
        float f0 = dinv[ns.x], f1 = dinv[ns.y], f2 = dinv[ns.z], f3 = dinv[ns.w];
        uint4 g0 = ROW(ns.x), g1 = ROW(ns.y), g2 = ROW(ns.z), g3 = ROW(ns.w);
        ACC8(h0, e0); ACC8(h1, e1); ACC8(h2, e2); ACC8(h3, e3);
        h0 = g0; h1 = g1; h2 = g2; h3 = g3;
        e0 = f0; e1 = f1; e2 = f2; e3 = f3;
        s = ns;
    }
    ACC8(h0, e0); ACC8(h1, e1); ACC8(h2, e2); ACC8(h3, e3);
#undef ACC8
#undef ROW

    float dv = dinv[v];
    const float4* b4 = (const float4*)bias;
    float4 bA = b4[fl * 2];
    float4 bB = b4[fl * 2 + 1];
    float r0 = fmaf(dv, a0, bA.x);
    float r1 = fmaf(dv, a1, bA.y);
    float r2 = fmaf(dv, a2, bA.z);
    float r3 = fmaf(dv, a3, bA.w);
    float r4 = fmaf(dv, a4, bB.x);
    float r5 = fmaf(dv, a5, bB.y);
    float r6 = fmaf(dv, a6, bB.z);
    float r7 = fmaf(dv, a7, bB.w);
    if (RELU_BF16OUT) {
        r0 = fmaxf(r0, 0.f); r1 = fmaxf(r1, 0.f);
        r2 = fmaxf(r2, 0.f); r3 = fmaxf(r3, 0.f);
        r4 = fmaxf(r4, 0.f); r5 = fmaxf(r5, 0.f);
        r6 = fmaxf(r6, 0.f); r7 = fmaxf(r7, 0.f);
        uint4 pk;
        pk.x = bf16_rne(r0) | (bf16_rne(r1) << 16);
        pk.y = bf16_rne(r2) | (bf16_rne(r3) << 16);
        pk.z = bf16_rne(r4) | (bf16_rne(r5) << 16);
        pk.w = bf16_rne(r6) | (bf16_rne(r7) << 16);
        ((uint4*)outv)[(size_t)v * 8 + fl] = pk;
    } else {
        float4* o = (float4*)outv + (size_t)v * 16 + fl * 2;
        o[0] = make_float4(r0, r1, r2, r3);
        o[1] = make_float4(r4, r5, r6, r7);
    }
}

extern "C" void kernel_launch(void* const* d_in, const int* in_sizes, int n_in,
                              void* d_out, int out_size, void* d_ws, size_t ws_size,
                              hipStream_t stream) {
    const float* x  = (const float*)d_in[0];
    const int*   ei = (const int*)d_in[1];  // harness delivers int32
    const float* W1 = (const float*)d_in[2];
    const float* b1 = (const float*)d_in[3];
    const float* W2 = (const float*)d_in[4];
    const float* b2 = (const float*)d_in[5];
    float* out      = (float*)d_out;

    const int N = in_sizes[0] / 64;
    const int E = in_sizes[1] / 2;
    const int* row = ei;
    const int* col = ei + E;
    const int T = E + N;
    const int NB = (N + BSZ - 1) >> BSH;
    const int numTiles = (T + PTILE - 1) / PTILE;

    char* p = (char*)d_ws;
    auto alloc = [&](size_t bytes) { void* r = (void*)p; p += (bytes + 255) & ~(size_t)255; return r; };
    int*      tcnt    = (int*)alloc((size_t)NB * numTiles * 4);
    int*      btot    = (int*)alloc((size_t)(NB + 1) * 4);
    int*      offsets = (int*)alloc((size_t)N * 4);
    int*      cnt     = (int*)alloc((size_t)N * 4);
    float*    dinv    = (float*)alloc((size_t)(N + 16) * 4);  // +sentinel N
    unsigned* pairs   = (unsigned*)alloc((size_t)NB * CAP * 4);
    int*      csrc    = (int*)alloc(((size_t)NB * CROW + 64) * 4);
    unsigned* hbuf    = (unsigned*)alloc((size_t)(N + 16) * 32 * 4);  // bf16, +zero row
    unsigned* abuf    = (unsigned*)alloc((size_t)(N + 16) * 32 * 4);  // bf16, +zero row

    const int nSlabs = (N + 16) / 16;  // covers zero sentinel row N
    const int GB = (N + NPB - 1) / NPB;

    k_cntgm<<<numTiles + GEMMB, 512, 0, stream>>>(col, E, N, NB, numTiles, tcnt,
                                                  x, W1, hbuf, nSlabs);
    k_scan<<<NB, 512, 0, stream>>>(tcnt, btot, NB, numTiles);
    k_scatter<<<numTiles, 512, 0, stream>>>(row, col, E, N, NB, numTiles, tcnt, pairs);
    k_bfill<<<NB, 1024, 0, stream>>>(pairs, btot, N, offsets, cnt, dinv, csrc);

    k_agg<true><<<GB, 256, 0, stream>>>((const uint4*)hbuf, offsets, cnt, csrc, dinv, b1, abuf, N);
    k_gemm<true><<<1024, 256, 0, stream>>>(abuf, W2, hbuf, N, nSlabs, 1024);
    k_agg<false><<<GB, 256, 0, stream>>>((const uint4*)hbuf, offsets, cnt, csrc, dinv, b2, out, N);
}